// Round 15
// baseline (351.447 us; speedup 1.0000x reference)
//
#include <hip/hip_runtime.h>
#include <cstddef>

#define DINL static __device__ __forceinline__

// collision-proof custom vector types (HIP headers own names like short8/float4)
typedef __attribute__((ext_vector_type(4))) float f4v;
typedef __attribute__((ext_vector_type(8))) short bh8;   // 8 bf16 bit patterns (4 VGPRs)
typedef __attribute__((ext_vector_type(4))) unsigned short us4;  // 4 bf16 (8 B)

// rot90 applied r times (counter-clockwise, numpy convention): rotated_r[i][j] = w[si][sj]
DINL void rot_src(int r, int K, int i, int j, int& si, int& sj) {
  switch (r & 3) {
    case 0:  si = i;       sj = j;       break;
    case 1:  si = j;       sj = K-1-i;   break;
    case 2:  si = K-1-i;   sj = K-1-j;   break;
    default: si = K-1-j;   sj = i;       break;
  }
}

DINL float sigmoidf(float s) { return 1.f / (1.f + __expf(-s)); }

// float -> bf16 bits, round-to-nearest-even
DINL unsigned short f2bf(float f) {
  unsigned u = __builtin_bit_cast(unsigned, f);
  u += 0x7fffu + ((u >> 16) & 1u);
  return (unsigned short)(u >> 16);
}
DINL float bf2f(unsigned short h) {
  unsigned u = ((unsigned)h) << 16;
  return __builtin_bit_cast(float, u);
}

// ---------------- parallel BN finalize from bucketed partials ----------------
DINL void bn_finalize_par(const float* __restrict__ partl,
                          const float* __restrict__ gamma, const float* __restrict__ beta,
                          float* st, float* l1, float* l2, int npix, int tid) {
  if (tid < 256) {
    int c = tid & 31, grp = tid >> 5;
    float s1 = 0.f, s2 = 0.f;
    #pragma unroll
    for (int k = 0; k < 8; ++k) {
      int bk = grp * 8 + k;
      s1 += partl[bk * 128 + c];
      s2 += partl[bk * 128 + 64 + c];
    }
    l1[tid] = s1; l2[tid] = s2;
  }
  __syncthreads();
  if (tid < 32) {
    float a = 0.f, q = 0.f;
    #pragma unroll
    for (int k = 0; k < 8; ++k) { a += l1[k * 32 + tid]; q += l2[k * 32 + tid]; }
    float N = 4.f * (float)npix;
    float m = a / N;
    float v = q / N - m * m;
    float inv = rsqrtf(v + 2e-5f);
    float sc = gamma[tid] * inv;
    st[tid] = sc;
    st[32 + tid] = beta[tid] - m * sc;
  }
  __syncthreads();
}

// ---------------- packed: weight prep + L1 attention + BN-bucket zero ----------------
// blocks [0,3168): prep_w; [3168,4192): att_lift (banded); [4192,4216): zero PART.
// All three are mutually independent (inputs only); branch is block-uniform.
__global__ void __launch_bounds__(256)
k_prep_att(const float* __restrict__ w2, const float* __restrict__ w3,
           const float* __restrict__ w4, const float* __restrict__ w5,
           const float* __restrict__ w6, const float* __restrict__ w7,
           unsigned short* __restrict__ wrot,
           const float* __restrict__ x, const float* __restrict__ aw1,
           float* __restrict__ att, float* __restrict__ part) {
  __shared__ float wsum[4][49];
  __shared__ float xs[12 * 48];
  int bid = blockIdx.x;
  if (bid < 3168) {
    // ---- weight prep: c' = g*32 + ci; bh8 wrot[r][tap][ks][mi][lane][j8] ----
    int idx = bid * 256 + threadIdx.x;
    const float* w; int OM, O, base;
    if (idx < 737280) {
      int L = idx / 147456; base = L * 147456; OM = 2; O = 32;
      w = (L == 0) ? w2 : (L == 1) ? w3 : (L == 2) ? w4 : (L == 3) ? w5 : w6;
    } else { base = 737280; OM = 1; O = 10; w = w7; }
    int local = idx - base;
    int j = local & 7; int t = local >> 3;
    int lanei = t & 63; t >>= 6;
    int mi = t % OM; t /= OM;
    int ks = t & 3; t >>= 2;
    int tap = t % 9; int r = t / 9;
    int n = lanei & 15, q = lanei >> 4;
    int o = mi * 16 + n;
    int ci = q * 8 + j;
    int gs = (ks - r) & 3;
    int ky = tap / 3, kx = tap % 3;
    int si, sj; rot_src(r, 3, ky, kx, si, sj);
    float val = (o < O) ? w[((o * 32 + ci) * 4 + gs) * 9 + si * 3 + sj] : 0.f;
    wrot[idx] = f2bf(val);
  } else if (bid < 4192) {
    // ---- layer-1 attention, LDS-banded (verified R6) ----
    const int H = 48, HW = H * H, BH = 6, NB = 8;
    int id = bid - 3168;
    int band = id % NB; int t = id / NB;
    int r = t & 3; int b = t >> 2;
    int row0 = band * BH;
    int base = row0 - 3;
    for (int i = threadIdx.x; i < 196; i += 256) {
      int rr = i / 49; int tt = i % 49;
      int ky = tt / 7, kx = tt % 7;
      int si, sj; rot_src(rr, 7, ky, kx, si, sj);
      wsum[rr][tt] = aw1[si * 7 + sj] + aw1[49 + si * 7 + sj];
    }
    const float* xb = x + b * HW;
    for (int i = threadIdx.x; i < 12 * 48; i += 256) {
      int rr = base + i / 48;
      xs[i] = ((unsigned)rr < (unsigned)H) ? xb[rr * H + (i % 48)] : 0.f;
    }
    __syncthreads();
    for (int i = threadIdx.x; i < BH * H; i += 256) {
      int yh = row0 + i / H; int xw = i % H;
      float s = 0.f;
      for (int ky = 0; ky < 7; ++ky) {
        int y = yh + ky - 3;
        if ((unsigned)y >= (unsigned)H) continue;
        for (int kx = 0; kx < 7; ++kx) {
          int xx = xw + kx - 3;
          if ((unsigned)xx >= (unsigned)H) continue;
          s += xs[(y - base) * H + xx] * wsum[r][ky * 7 + kx];
        }
      }
      att[(size_t)(b * 4 + r) * HW + yh * H + xw] = sigmoidf(s);
    }
  } else {
    // ---- zero the 6x8192 BN partial buckets ----
    int zb = bid - 4192;                  // [0,24)
    int off = zb * 2048 + threadIdx.x;
    #pragma unroll
    for (int k = 0; k < 8; ++k) part[off + k * 256] = 0.f;
  }
}

// ---------------- layer 1: LDS-tiled lifting conv + BN partial stats ----------------
__global__ void __launch_bounds__(256)
k_conv_lift(const float* __restrict__ x, const float* __restrict__ att,
            const float* __restrict__ w, const float* __restrict__ bias,
            unsigned short* __restrict__ y, float* __restrict__ partl) {
  const int HO = 46;
  __shared__ float xs[3 * 48];
  __shared__ float as[4][3 * 48];
  __shared__ float wsm[288];
  __shared__ float bs[32];
  __shared__ float bnred[64];
  int id = blockIdx.x;
  int yo = id % HO; int b = id / HO;

  for (int i = threadIdx.x; i < 144; i += 256)
    xs[i] = x[b * 2304 + (yo + i / 48) * 48 + (i % 48)];
  for (int i = threadIdx.x; i < 576; i += 256) {
    int r = i / 144; int rem = i % 144;
    as[r][rem] = att[(b * 4 + r) * 2304 + (yo + rem / 48) * 48 + (rem % 48)];
  }
  for (int i = threadIdx.x; i < 288; i += 256) wsm[i] = w[i];
  if (threadIdx.x < 32) bs[threadIdx.x] = bias[threadIdx.x];
  if (threadIdx.x < 64) bnred[threadIdx.x] = 0.f;
  __syncthreads();

  int o = threadIdx.x & 31;
  int cl = threadIdx.x >> 5;
  float wreg[9];
  #pragma unroll
  for (int i = 0; i < 9; ++i) wreg[i] = wsm[o * 9 + i];
  float bv = bs[o];
  float sacc = 0.f, qacc = 0.f;

  for (int c8 = 0; c8 < 6; ++c8) {
    int col = c8 * 8 + cl;
    if (col < HO) {
      float xv[9];
      #pragma unroll
      for (int ky = 0; ky < 3; ++ky)
        #pragma unroll
        for (int kx = 0; kx < 3; ++kx)
          xv[ky * 3 + kx] = xs[ky * 48 + col + kx];
      unsigned short* yp = y + ((size_t)b * 2116 + yo * HO + col) * 128 + o;
      #pragma unroll
      for (int r = 0; r < 4; ++r) {
        float acc = bv;
        #pragma unroll
        for (int ky = 0; ky < 3; ++ky)
          #pragma unroll
          for (int kx = 0; kx < 3; ++kx) {
            int si, sj; rot_src(r, 3, ky, kx, si, sj);  // folds: r,ky,kx constant
            acc = fmaf(as[r][ky * 48 + col + kx] * xv[ky * 3 + kx], wreg[si * 3 + sj], acc);
          }
        yp[r * 32] = f2bf(acc);
        sacc += acc; qacc += acc * acc;
      }
    }
  }
  atomicAdd(&bnred[o], sacc);
  atomicAdd(&bnred[32 + o], qacc);
  __syncthreads();
  if (threadIdx.x < 64) {
    int bucket = blockIdx.x & 63;
    int c = threadIdx.x & 31;
    int off = (threadIdx.x < 32) ? c : (64 + c);
    atomicAdd(&partl[bucket * 128 + off], bnred[threadIdx.x]);
  }
}

// ---------------- MFMA attentive GG conv (fused att, single-buffer LDS) ----------------
// v10 = R14 with the LDS double-buffer dropped (xa single): 52.2 -> ~27.3 KB
// LDS => 3 -> 5 blocks/CU. T14 kept: issue(1) targets REGISTERS so it still
// overlaps mfma(0); only the wlds(1) LDS write moves behind one extra barrier.
// as_l aliases xa (read strictly before wlds(0) writes). Bit-identical math.
template<int H, int OM, int O, int OSTR, bool BNS>
__global__ void __launch_bounds__(256)
k_conv_mfma(const unsigned short* __restrict__ xn, const unsigned short* __restrict__ amap,
            const float* __restrict__ aw,
            const unsigned short* __restrict__ wl, const float* __restrict__ bias,
            unsigned short* __restrict__ y, float* __restrict__ partl) {
  constexpr int HO = H - 2, HW = H * H;
  constexpr int TR = 8, TC = 16, WR = TR + 2, WC = TC + 2, CGH = 68;
  constexpr int NRT = (HO + TR - 1) / TR, NCT = (HO + TC - 1) / TC;
  constexpr int NPIX = WR * WC;            // 180
  constexpr int NCH = NPIX * 8;            // 1440 16B-chunks per half
  constexpr int NST = (NCH + 255) / 256;   // 6
  constexpr int RH = WR + 6, RW = WC + 6;  // amap halo region 16 x 24
  constexpr int RWP = RW + 1;              // padded row stride
  __shared__ __align__(16) unsigned short xa[NPIX * CGH];  // 24,480 B (single)
  __shared__ float bnred[128];
  __shared__ float wsa_l[4][49], wsx_l[4][49];   // this block's r only (1568 B)
  __shared__ float att_l[NPIX];                  // 720 B

  // XCD swizzle: blockIdx.x % 8 <-> b % 8
  int id = blockIdx.x;
  int slot = id & 7; int k = id >> 3;
  int tile = k % (NRT * NCT); k /= (NRT * NCT);
  int r = k & 3; int bhi = k >> 2;
  int b = bhi * 8 + slot;
  int rt = tile / NCT, ct = tile % NCT;
  int row0 = rt * TR, c0 = ct * TC;

  const unsigned short* xb = xn + (size_t)b * HW * 128;
  const unsigned short* ab8 = amap + (size_t)b * HW * 8;

  int tid = threadIdx.x;
  int lane = tid & 63;
  int wv = tid >> 6;
  int n = lane & 15, quad = lane >> 4;

  f4v acc[OM][2];
  #pragma unroll
  for (int mi = 0; mi < OM; ++mi)
    #pragma unroll
    for (int ri = 0; ri < 2; ++ri) {
      acc[mi][ri][0] = 0.f; acc[mi][ri][1] = 0.f;
      acc[mi][ri][2] = 0.f; acc[mi][ri][3] = 0.f;
    }

  const bh8* wa = (const bh8*)wl + (size_t)r * 9 * 4 * OM * 64 + lane;

  // 4-deep weight prefetch ring (consume-then-load; validated R3)
  bh8 wqa[4], wqb[4];
  auto wload = [&](int s) {
    int hh = s / 18, tt = s % 18, tp = tt >> 1, kk = tt & 1, ks2 = hh * 2 + kk;
    wqa[s & 3] = wa[(size_t)((tp * 4 + ks2) * OM + 0) * 64];
    if constexpr (OM == 2)
      wqb[s & 3] = wa[(size_t)((tp * 4 + ks2) * OM + 1) * 64];
  };

  // register staging: issue all 6 chunk loads back-to-back (1 latency round-trip)
  bh8 sx[NST];
  auto issue = [&](int half) {
    #pragma unroll
    for (int i = 0; i < NST; ++i) {
      int u = tid + i * 256;
      if (i + 1 < NST || u < NCH) {
        int ch = u & 7; int pix = u >> 3;
        int wr = pix / WC, wc = pix % WC;
        int row = row0 + wr; if (row > H - 1) row = H - 1;
        int col = c0 + wc;  if (col > H - 1) col = H - 1;
        int p = row * H + col;
        sx[i] = *(const bh8*)(xb + (size_t)p * 128 + half * 64 + ch * 8);
      }
    }
  };
  auto wlds = [&]() {
    #pragma unroll
    for (int i = 0; i < NST; ++i) {
      int u = tid + i * 256;
      if (i + 1 < NST || u < NCH) {
        int ch = u & 7; int pix = u >> 3;
        float av = att_l[pix];
        bh8 v;
        #pragma unroll
        for (int j2 = 0; j2 < 8; ++j2)
          v[j2] = (short)f2bf(bf2f((unsigned short)sx[i][j2]) * av);
        *(bh8*)&xa[pix * CGH + ch * 8] = v;
      }
    }
  };
  auto mfma_half = [&](int half) {
    #pragma unroll
    for (int t = 0; t < 18; ++t) {
      const int s = half * 18 + t;
      // consume ring slot first (locals keep old value live), then prefetch
      bh8 a0 = wqa[s & 3];
      bh8 a1;
      if constexpr (OM == 2) a1 = wqb[s & 3];
      if (s + 4 < 36) wload(s + 4);
      const int tap = t >> 1, kl = t & 1;
      const int ky = tap / 3, kx = tap % 3;
      int pb0 = ((2 * wv + ky) * WC + n + kx) * CGH;
      int pb1 = pb0 + WC * CGH;
      bh8 b0 = *(const bh8*)&xa[pb0 + kl * 32 + quad * 8];
      bh8 b1 = *(const bh8*)&xa[pb1 + kl * 32 + quad * 8];
      acc[0][0] = __builtin_amdgcn_mfma_f32_16x16x32_bf16(a0, b0, acc[0][0], 0, 0, 0);
      acc[0][1] = __builtin_amdgcn_mfma_f32_16x16x32_bf16(a0, b1, acc[0][1], 0, 0, 0);
      if constexpr (OM == 2) {
        acc[1][0] = __builtin_amdgcn_mfma_f32_16x16x32_bf16(a1, b0, acc[1][0], 0, 0, 0);
        acc[1][1] = __builtin_amdgcn_mfma_f32_16x16x32_bf16(a1, b1, acc[1][1], 0, 0, 0);
      }
    }
  };

  // amap halo staging buffer aliases xa (read strictly before wlds(0) writes);
  // padded stride RWP: RH*RWP*8 = 3200 ushorts = 6400 B << 24,480 B
  unsigned short* as_l = &xa[0];

  // stage this block's rotated attention weights (r fixed)
  for (int i = tid; i < 196; i += 256) {
    int g = i / 49; int t = i % 49;
    int ky = t / 7, kx = t % 7;
    int si, sj; rot_src(r, 7, ky, kx, si, sj);
    int gs = (g - r) & 3;
    wsa_l[g][t] = aw[gs * 49 + si * 7 + sj];
    wsx_l[g][t] = aw[(4 + gs) * 49 + si * 7 + sj];
  }
  // stage amap halo region [row0-3, row0+WR+3) x [c0-3, c0+WC+3), coalesced
  for (int i = tid; i < RH * RW; i += 256) {
    int hr = i / RW, hc = i % RW;
    int gy = row0 - 3 + hr;
    int gx = c0 - 3 + hc;
    bh8 v;
    if ((unsigned)gy < (unsigned)H && (unsigned)gx < (unsigned)H)
      v = *(const bh8*)(ab8 + ((size_t)gy * H + gx) * 8);
    else
      v = (bh8)(short)0;   // never read (tap skip conditions), safe filler
    *(bh8*)&as_l[(hr * RWP + hc) * 8] = v;
  }
  wload(0); wload(1); wload(2); wload(3);
  issue(0);                 // x loads in flight under the att compute
  __syncthreads();          // wsa_l/wsx_l/as_l ready

  // per-tile attention from LDS (tap order verbatim from k_att_gg);
  // att accumulates into registers -> safe to overwrite as_l afterwards
  float att_s = 0.f;
  int yh0 = 0, xw0 = 0;
  if (tid < NPIX) {
    yh0 = row0 + tid / WC; if (yh0 > H - 1) yh0 = H - 1;
    xw0 = c0 + tid % WC;   if (xw0 > H - 1) xw0 = H - 1;
    for (int ky = 0; ky < 7; ++ky) {
      int y = yh0 + ky - 3;
      if ((unsigned)y >= (unsigned)H) continue;
      for (int kx = 0; kx < 7; ++kx) {
        int xx = xw0 + kx - 3;
        if ((unsigned)xx >= (unsigned)H) continue;
        int tp = ky * 7 + kx;
        bh8 av = *(const bh8*)&as_l[((y - (row0 - 3)) * RWP + (xx - (c0 - 3))) * 8];
        #pragma unroll
        for (int g = 0; g < 4; ++g)
          att_s += bf2f((unsigned short)av[g]) * wsa_l[g][tp]
                 + bf2f((unsigned short)av[4 + g]) * wsx_l[g][tp];
      }
    }
  }
  __syncthreads();          // as_l readers done (xa free for wlds(0))
  if (tid < NPIX) att_l[tid] = sigmoidf(att_s);
  __syncthreads();          // att_l ready

  wlds();                   // half-0 staged into xa
  __syncthreads();
  issue(1);                 // half-1 loads -> REGISTERS, overlap mfma(0)
  mfma_half(0);
  __syncthreads();          // all reads of xa (half 0) done
  wlds();                   // half-1 staged into xa
  __syncthreads();
  mfma_half(1);

  // epilogue: C/D col=lane&15 (spatial), row=quad*4+reg (o); c' = r*O + o
  float sv[OM * 4], qv[OM * 4];
  #pragma unroll
  for (int e = 0; e < OM * 4; ++e) { sv[e] = 0.f; qv[e] = 0.f; }
  #pragma unroll
  for (int mi = 0; mi < OM; ++mi)
    #pragma unroll
    for (int ri = 0; ri < 2; ++ri) {
      int prow = row0 + 2 * wv + ri;
      int col = c0 + n;
      if (prow < HO && col < HO) {
        unsigned short* yp = y + ((size_t)b * HO * HO + prow * HO + col) * OSTR;
        int o0 = mi * 16 + quad * 4;
        f4v v = acc[mi][ri];
        if constexpr (O == 32) {
          us4 w4;
          #pragma unroll
          for (int reg = 0; reg < 4; ++reg) {
            float val = v[reg] + bias[o0 + reg];
            w4[reg] = f2bf(val);
            if constexpr (BNS) { sv[mi * 4 + reg] += val; qv[mi * 4 + reg] += val * val; }
          }
          *(us4*)(yp + r * 32 + o0) = w4;
        } else {
          #pragma unroll
          for (int reg = 0; reg < 4; ++reg) {
            int o = o0 + reg;
            if (o < O) yp[r * O + o] = f2bf(v[reg] + bias[o]);
          }
        }
      }
    }

  if constexpr (BNS) {
    #pragma unroll
    for (int e = 0; e < OM * 4; ++e) {
      #pragma unroll
      for (int off = 1; off < 16; off <<= 1) {
        sv[e] += __shfl_xor(sv[e], off);
        qv[e] += __shfl_xor(qv[e], off);
      }
    }
    if (threadIdx.x < 128) bnred[threadIdx.x] = 0.f;
    __syncthreads();
    if (n == 0) {
      #pragma unroll
      for (int e = 0; e < OM * 4; ++e) {
        int o = (e >> 2) * 16 + quad * 4 + (e & 3);
        atomicAdd(&bnred[o], sv[e]);
        atomicAdd(&bnred[64 + o], qv[e]);
      }
    }
    __syncthreads();
    if (threadIdx.x < 128)
      atomicAdd(&partl[(blockIdx.x & 63) * 128 + threadIdx.x], bnred[threadIdx.x]);
  }
}

// ---------------- pixel-parallel post (L1..L6 part A): BN+ReLU(+pool)+amap ----------------
// thread = (output pixel, rotation group g). Same accumulation order as the
// original fused post -> bit-identical. Also serves L1 (HIN=HOUT=46).
template<int HIN, int HOUT, bool POOL>
__global__ void __launch_bounds__(256)
k_postA(const unsigned short* __restrict__ yr, const float* __restrict__ partl,
        const float* __restrict__ gamma, const float* __restrict__ beta,
        unsigned short* __restrict__ xn, unsigned short* __restrict__ amap) {
  __shared__ float st[64];
  __shared__ float l1[256], l2[256];
  bn_finalize_par(partl, gamma, beta, st, l1, l2, 32 * HIN * HIN, threadIdx.x);
  int idx = blockIdx.x * 256 + threadIdx.x;
  if (idx >= 32 * HOUT * HOUT * 4) return;
  int g = idx & 3; int p = idx >> 2;
  int col = p % HOUT; int t = p / HOUT;
  int row = t % HOUT; int b = t / HOUT;
  float sm = 0.f, mx = -1e30f;
  unsigned short* xp = xn + (size_t)p * 128 + g * 32;
  if constexpr (POOL) {
    const unsigned short* p00 =
        yr + ((size_t)b * HIN * HIN + (row * 2) * HIN + col * 2) * 128 + g * 32;
    #pragma unroll
    for (int k = 0; k < 4; ++k) {
      bh8 r0 = *(const bh8*)(p00 + k * 8);
      bh8 r1 = *(const bh8*)(p00 + 128 + k * 8);
      bh8 r2 = *(const bh8*)(p00 + (size_t)HIN * 128 + k * 8);
      bh8 r3 = *(const bh8*)(p00 + (size_t)(HIN + 1) * 128 + k * 8);
      bh8 w;
      #pragma unroll
      for (int e = 0; e < 8; ++e) {
        float sc = st[k * 8 + e], sh = st[32 + k * 8 + e];
        float a0 = fmaxf(fmaf(bf2f((unsigned short)r0[e]), sc, sh), 0.f);
        float a1 = fmaxf(fmaf(bf2f((unsigned short)r1[e]), sc, sh), 0.f);
        float a2 = fmaxf(fmaf(bf2f((unsigned short)r2[e]), sc, sh), 0.f);
        float a3 = fmaxf(fmaf(bf2f((unsigned short)r3[e]), sc, sh), 0.f);
        float val = fmaxf(fmaxf(a0, a1), fmaxf(a2, a3));
        w[e] = (short)f2bf(val);
        sm += val; mx = fmaxf(mx, val);
      }
      *(bh8*)(xp + k * 8) = w;
    }
  } else {
    const unsigned short* yp = yr + (size_t)p * 128 + g * 32;
    #pragma unroll
    for (int k = 0; k < 4; ++k) {
      bh8 raw = *(const bh8*)(yp + k * 8);
      bh8 w;
      #pragma unroll
      for (int e = 0; e < 8; ++e) {
        float v = fmaxf(fmaf(bf2f((unsigned short)raw[e]), st[k * 8 + e], st[32 + k * 8 + e]), 0.f);
        w[e] = (short)f2bf(v);
        sm += v;
        mx = fmaxf(mx, v);
      }
      *(bh8*)(xp + k * 8) = w;
    }
  }
  amap[(size_t)p * 8 + g] = f2bf(sm * (1.f / 32.f));
  amap[(size_t)p * 8 + 4 + g] = f2bf(mx);
}

// ---------------- final: rotation max + spatial mean ----------------
__global__ void k_final(const unsigned short* __restrict__ y7, float* __restrict__ out) {
  int idx = blockIdx.x * blockDim.x + threadIdx.x;
  if (idx >= 320) return;
  int o = idx % 10; int b = idx / 10;
  const unsigned short* p = y7 + (size_t)b * 144 * 40;
  float s = 0.f;
  for (int sp = 0; sp < 144; ++sp) {
    const unsigned short* q = p + sp * 40 + o;
    float m = fmaxf(fmaxf(bf2f(q[0]), bf2f(q[10])), fmaxf(bf2f(q[20]), bf2f(q[30])));
    s += m;
  }
  out[idx] = s * (1.f / 144.f);
}

// ---------------- host ----------------

extern "C" void kernel_launch(void* const* d_in, const int* in_sizes, int n_in,
                              void* d_out, int out_size, void* d_ws, size_t ws_size,
                              hipStream_t stream) {
  (void)in_sizes; (void)n_in; (void)out_size; (void)ws_size;
  const float* x   = (const float*)d_in[0];
  const float* w1  = (const float*)d_in[1];
  const float* b1  = (const float*)d_in[2];
  const float* aw1 = (const float*)d_in[3];
  const float* W[6];  const float* BI[6]; const float* AW[6];
  for (int i = 0; i < 6; ++i) {
    W[i]  = (const float*)d_in[4 + 3 * i];
    BI[i] = (const float*)d_in[5 + 3 * i];
    AW[i] = (const float*)d_in[6 + 3 * i];
  }
  const float* G[6]; const float* BE[6];
  for (int i = 0; i < 6; ++i) {
    G[i]  = (const float*)d_in[22 + 2 * i];
    BE[i] = (const float*)d_in[23 + 2 * i];
  }
  float* out = (float*)d_out;

  // workspace (floats): ~38.8 MB
  float* ws = (float*)d_ws;
  unsigned short* YR = (unsigned short*)ws;                  // raw conv out bf16
  unsigned short* XN = (unsigned short*)(ws + 4333568);      // normalized xn bf16
  unsigned short* AMAP = (unsigned short*)(ws + 8667136);    // amap, 541,696 ush
  float* ATT = ws + 8937984;                                 // 294,912 (L1 lift only)
  unsigned short* WROT = (unsigned short*)(ws + 9232896);    // 811,008 ush
  float* PART  = ws + 9638400;                               // 6 layers x 8192

  auto cdiv = [](int a, int b) { return (a + b - 1) / b; };
  float* PL[6];
  for (int i = 0; i < 6; ++i) PL[i] = PART + i * 8192;

  // packed: weight prep (3168) + L1 attention (1024) + PART zero (24)
  k_prep_att<<<dim3(4216), dim3(256), 0, stream>>>(
      W[0], W[1], W[2], W[3], W[4], W[5], WROT, x, aw1, ATT, PART);
  const unsigned short* WL[6];
  for (int i = 0; i < 5; ++i) WL[i] = WROT + i * 147456;
  WL[5] = WROT + 737280;

  // ---- layer 1: lifting conv (stats fused) + pixel-parallel post ----
  k_conv_lift<<<dim3(32 * 46), dim3(256), 0, stream>>>(x, ATT, w1, b1, YR, PL[0]);
  k_postA<46, 46, false><<<dim3(cdiv(32 * 46 * 46 * 4, 256)), dim3(256), 0, stream>>>(YR, PL[0], G[0], BE[0], XN, AMAP);
  // ---- layer 2 (H=46 -> 44, att fused from AMAP+AW[0]) + post (pool) ----
  k_conv_mfma<46, 2, 32, 128, true><<<dim3(128 * 6 * 3), dim3(256), 0, stream>>>(XN, AMAP, AW[0], WL[0], BI[0], YR, PL[1]);
  k_postA<44, 22, true><<<dim3(cdiv(32 * 22 * 22 * 4, 256)), dim3(256), 0, stream>>>(YR, PL[1], G[1], BE[1], XN, AMAP);
  // ---- layer 3 (22 -> 20) ----
  k_conv_mfma<22, 2, 32, 128, true><<<dim3(128 * 3 * 2), dim3(256), 0, stream>>>(XN, AMAP, AW[1], WL[1], BI[1], YR, PL[2]);
  k_postA<20, 20, false><<<dim3(cdiv(32 * 20 * 20 * 4, 256)), dim3(256), 0, stream>>>(YR, PL[2], G[2], BE[2], XN, AMAP);
  // ---- layer 4 (20 -> 18) ----
  k_conv_mfma<20, 2, 32, 128, true><<<dim3(128 * 3 * 2), dim3(256), 0, stream>>>(XN, AMAP, AW[2], WL[2], BI[2], YR, PL[3]);
  k_postA<18, 18, false><<<dim3(cdiv(32 * 18 * 18 * 4, 256)), dim3(256), 0, stream>>>(YR, PL[3], G[3], BE[3], XN, AMAP);
  // ---- layer 5 (18 -> 16) ----
  k_conv_mfma<18, 2, 32, 128, true><<<dim3(128 * 2 * 1), dim3(256), 0, stream>>>(XN, AMAP, AW[3], WL[3], BI[3], YR, PL[4]);
  k_postA<16, 16, false><<<dim3(cdiv(32 * 16 * 16 * 4, 256)), dim3(256), 0, stream>>>(YR, PL[4], G[4], BE[4], XN, AMAP);
  // ---- layer 6 (16 -> 14) ----
  k_conv_mfma<16, 2, 32, 128, true><<<dim3(128 * 2 * 1), dim3(256), 0, stream>>>(XN, AMAP, AW[4], WL[4], BI[4], YR, PL[5]);
  k_postA<14, 14, false><<<dim3(cdiv(32 * 14 * 14 * 4, 256)), dim3(256), 0, stream>>>(YR, PL[5], G[5], BE[5], XN, AMAP);
  // ---- layer 7 (14 -> 12, O=10, no BN) ----
  k_conv_mfma<14, 1, 10, 40, false><<<dim3(128 * 2 * 1), dim3(256), 0, stream>>>(XN, AMAP, AW[5], WL[5], BI[5], YR, nullptr);
  // ---- rotation max + spatial mean ----
  k_final<<<dim3(5), dim3(64), 0, stream>>>(YR, out);
}

// Round 16
// 347.010 us; speedup vs baseline: 1.0128x; 1.0128x over previous
//
#include <hip/hip_runtime.h>
#include <cstddef>

#define DINL static __device__ __forceinline__

// collision-proof custom vector types (HIP headers own names like short8/float4)
typedef __attribute__((ext_vector_type(4))) float f4v;
typedef __attribute__((ext_vector_type(8))) short bh8;   // 8 bf16 bit patterns (4 VGPRs)
typedef __attribute__((ext_vector_type(4))) unsigned short us4;  // 4 bf16 (8 B)

// rot90 applied r times (counter-clockwise, numpy convention): rotated_r[i][j] = w[si][sj]
DINL void rot_src(int r, int K, int i, int j, int& si, int& sj) {
  switch (r & 3) {
    case 0:  si = i;       sj = j;       break;
    case 1:  si = j;       sj = K-1-i;   break;
    case 2:  si = K-1-i;   sj = K-1-j;   break;
    default: si = K-1-j;   sj = i;       break;
  }
}

DINL float sigmoidf(float s) { return 1.f / (1.f + __expf(-s)); }

// float -> bf16 bits, round-to-nearest-even
DINL unsigned short f2bf(float f) {
  unsigned u = __builtin_bit_cast(unsigned, f);
  u += 0x7fffu + ((u >> 16) & 1u);
  return (unsigned short)(u >> 16);
}
DINL float bf2f(unsigned short h) {
  unsigned u = ((unsigned)h) << 16;
  return __builtin_bit_cast(float, u);
}

// ---------------- parallel BN finalize from bucketed partials ----------------
DINL void bn_finalize_par(const float* __restrict__ partl,
                          const float* __restrict__ gamma, const float* __restrict__ beta,
                          float* st, float* l1, float* l2, int npix, int tid) {
  if (tid < 256) {
    int c = tid & 31, grp = tid >> 5;
    float s1 = 0.f, s2 = 0.f;
    #pragma unroll
    for (int k = 0; k < 8; ++k) {
      int bk = grp * 8 + k;
      s1 += partl[bk * 128 + c];
      s2 += partl[bk * 128 + 64 + c];
    }
    l1[tid] = s1; l2[tid] = s2;
  }
  __syncthreads();
  if (tid < 32) {
    float a = 0.f, q = 0.f;
    #pragma unroll
    for (int k = 0; k < 8; ++k) { a += l1[k * 32 + tid]; q += l2[k * 32 + tid]; }
    float N = 4.f * (float)npix;
    float m = a / N;
    float v = q / N - m * m;
    float inv = rsqrtf(v + 2e-5f);
    float sc = gamma[tid] * inv;
    st[tid] = sc;
    st[32 + tid] = beta[tid] - m * sc;
  }
  __syncthreads();
}

// ---------------- packed: weight prep + L1 attention + BN-bucket zero ----------------
// blocks [0,3168): prep_w; [3168,4192): att_lift (banded); [4192,4216): zero PART.
// All three are mutually independent (inputs only); branch is block-uniform.
__global__ void __launch_bounds__(256)
k_prep_att(const float* __restrict__ w2, const float* __restrict__ w3,
           const float* __restrict__ w4, const float* __restrict__ w5,
           const float* __restrict__ w6, const float* __restrict__ w7,
           unsigned short* __restrict__ wrot,
           const float* __restrict__ x, const float* __restrict__ aw1,
           float* __restrict__ att, float* __restrict__ part) {
  __shared__ float wsum[4][49];
  __shared__ float xs[12 * 48];
  int bid = blockIdx.x;
  if (bid < 3168) {
    // ---- weight prep: c' = g*32 + ci; bh8 wrot[r][tap][ks][mi][lane][j8] ----
    int idx = bid * 256 + threadIdx.x;
    const float* w; int OM, O, base;
    if (idx < 737280) {
      int L = idx / 147456; base = L * 147456; OM = 2; O = 32;
      w = (L == 0) ? w2 : (L == 1) ? w3 : (L == 2) ? w4 : (L == 3) ? w5 : w6;
    } else { base = 737280; OM = 1; O = 10; w = w7; }
    int local = idx - base;
    int j = local & 7; int t = local >> 3;
    int lanei = t & 63; t >>= 6;
    int mi = t % OM; t /= OM;
    int ks = t & 3; t >>= 2;
    int tap = t % 9; int r = t / 9;
    int n = lanei & 15, q = lanei >> 4;
    int o = mi * 16 + n;
    int ci = q * 8 + j;
    int gs = (ks - r) & 3;
    int ky = tap / 3, kx = tap % 3;
    int si, sj; rot_src(r, 3, ky, kx, si, sj);
    float val = (o < O) ? w[((o * 32 + ci) * 4 + gs) * 9 + si * 3 + sj] : 0.f;
    wrot[idx] = f2bf(val);
  } else if (bid < 4192) {
    // ---- layer-1 attention, LDS-banded (verified R6) ----
    const int H = 48, HW = H * H, BH = 6, NB = 8;
    int id = bid - 3168;
    int band = id % NB; int t = id / NB;
    int r = t & 3; int b = t >> 2;
    int row0 = band * BH;
    int base = row0 - 3;
    for (int i = threadIdx.x; i < 196; i += 256) {
      int rr = i / 49; int tt = i % 49;
      int ky = tt / 7, kx = tt % 7;
      int si, sj; rot_src(rr, 7, ky, kx, si, sj);
      wsum[rr][tt] = aw1[si * 7 + sj] + aw1[49 + si * 7 + sj];
    }
    const float* xb = x + b * HW;
    for (int i = threadIdx.x; i < 12 * 48; i += 256) {
      int rr = base + i / 48;
      xs[i] = ((unsigned)rr < (unsigned)H) ? xb[rr * H + (i % 48)] : 0.f;
    }
    __syncthreads();
    for (int i = threadIdx.x; i < BH * H; i += 256) {
      int yh = row0 + i / H; int xw = i % H;
      float s = 0.f;
      for (int ky = 0; ky < 7; ++ky) {
        int y = yh + ky - 3;
        if ((unsigned)y >= (unsigned)H) continue;
        for (int kx = 0; kx < 7; ++kx) {
          int xx = xw + kx - 3;
          if ((unsigned)xx >= (unsigned)H) continue;
          s += xs[(y - base) * H + xx] * wsum[r][ky * 7 + kx];
        }
      }
      att[(size_t)(b * 4 + r) * HW + yh * H + xw] = sigmoidf(s);
    }
  } else {
    // ---- zero the 6x8192 BN partial buckets ----
    int zb = bid - 4192;                  // [0,24)
    int off = zb * 2048 + threadIdx.x;
    #pragma unroll
    for (int k = 0; k < 8; ++k) part[off + k * 256] = 0.f;
  }
}

// ---------------- layer 1: LDS-tiled lifting conv + BN partial stats ----------------
__global__ void __launch_bounds__(256)
k_conv_lift(const float* __restrict__ x, const float* __restrict__ att,
            const float* __restrict__ w, const float* __restrict__ bias,
            unsigned short* __restrict__ y, float* __restrict__ partl) {
  const int HO = 46;
  __shared__ float xs[3 * 48];
  __shared__ float as[4][3 * 48];
  __shared__ float wsm[288];
  __shared__ float bs[32];
  __shared__ float bnred[64];
  int id = blockIdx.x;
  int yo = id % HO; int b = id / HO;

  for (int i = threadIdx.x; i < 144; i += 256)
    xs[i] = x[b * 2304 + (yo + i / 48) * 48 + (i % 48)];
  for (int i = threadIdx.x; i < 576; i += 256) {
    int r = i / 144; int rem = i % 144;
    as[r][rem] = att[(b * 4 + r) * 2304 + (yo + rem / 48) * 48 + (rem % 48)];
  }
  for (int i = threadIdx.x; i < 288; i += 256) wsm[i] = w[i];
  if (threadIdx.x < 32) bs[threadIdx.x] = bias[threadIdx.x];
  if (threadIdx.x < 64) bnred[threadIdx.x] = 0.f;
  __syncthreads();

  int o = threadIdx.x & 31;
  int cl = threadIdx.x >> 5;
  float wreg[9];
  #pragma unroll
  for (int i = 0; i < 9; ++i) wreg[i] = wsm[o * 9 + i];
  float bv = bs[o];
  float sacc = 0.f, qacc = 0.f;

  for (int c8 = 0; c8 < 6; ++c8) {
    int col = c8 * 8 + cl;
    if (col < HO) {
      float xv[9];
      #pragma unroll
      for (int ky = 0; ky < 3; ++ky)
        #pragma unroll
        for (int kx = 0; kx < 3; ++kx)
          xv[ky * 3 + kx] = xs[ky * 48 + col + kx];
      unsigned short* yp = y + ((size_t)b * 2116 + yo * HO + col) * 128 + o;
      #pragma unroll
      for (int r = 0; r < 4; ++r) {
        float acc = bv;
        #pragma unroll
        for (int ky = 0; ky < 3; ++ky)
          #pragma unroll
          for (int kx = 0; kx < 3; ++kx) {
            int si, sj; rot_src(r, 3, ky, kx, si, sj);  // folds: r,ky,kx constant
            acc = fmaf(as[r][ky * 48 + col + kx] * xv[ky * 3 + kx], wreg[si * 3 + sj], acc);
          }
        yp[r * 32] = f2bf(acc);
        sacc += acc; qacc += acc * acc;
      }
    }
  }
  atomicAdd(&bnred[o], sacc);
  atomicAdd(&bnred[32 + o], qacc);
  __syncthreads();
  if (threadIdx.x < 64) {
    int bucket = blockIdx.x & 63;
    int c = threadIdx.x & 31;
    int off = (threadIdx.x < 32) ? c : (64 + c);
    atomicAdd(&partl[bucket * 128 + off], bnred[threadIdx.x]);
  }
}

// ---------------- MFMA attentive GG conv (fused per-tile attention, LDS amap) ----------------
// v9 (best, R14): fused att from AMAP staged into LDS halo (padded stride RWP),
// dbuf xa[2], T14 register staging, 4-deep weight ring. Bit-identical math.
template<int H, int OM, int O, int OSTR, bool BNS>
__global__ void __launch_bounds__(256)
k_conv_mfma(const unsigned short* __restrict__ xn, const unsigned short* __restrict__ amap,
            const float* __restrict__ aw,
            const unsigned short* __restrict__ wl, const float* __restrict__ bias,
            unsigned short* __restrict__ y, float* __restrict__ partl) {
  constexpr int HO = H - 2, HW = H * H;
  constexpr int TR = 8, TC = 16, WR = TR + 2, WC = TC + 2, CGH = 68;
  constexpr int NRT = (HO + TR - 1) / TR, NCT = (HO + TC - 1) / TC;
  constexpr int NPIX = WR * WC;            // 180
  constexpr int NCH = NPIX * 8;            // 1440 16B-chunks per half
  constexpr int NST = (NCH + 255) / 256;   // 6
  constexpr int RH = WR + 6, RW = WC + 6;  // amap halo region 16 x 24
  constexpr int RWP = RW + 1;              // padded row stride
  __shared__ __align__(16) unsigned short xa[2][NPIX * CGH];  // 2 x 24,480 B
  __shared__ float bnred[128];
  __shared__ float wsa_l[4][49], wsx_l[4][49];   // this block's r only (1568 B)
  __shared__ float att_l[NPIX];                  // 720 B

  // XCD swizzle: blockIdx.x % 8 <-> b % 8
  int id = blockIdx.x;
  int slot = id & 7; int k = id >> 3;
  int tile = k % (NRT * NCT); k /= (NRT * NCT);
  int r = k & 3; int bhi = k >> 2;
  int b = bhi * 8 + slot;
  int rt = tile / NCT, ct = tile % NCT;
  int row0 = rt * TR, c0 = ct * TC;

  const unsigned short* xb = xn + (size_t)b * HW * 128;
  const unsigned short* ab8 = amap + (size_t)b * HW * 8;

  int tid = threadIdx.x;
  int lane = tid & 63;
  int wv = tid >> 6;
  int n = lane & 15, quad = lane >> 4;

  f4v acc[OM][2];
  #pragma unroll
  for (int mi = 0; mi < OM; ++mi)
    #pragma unroll
    for (int ri = 0; ri < 2; ++ri) {
      acc[mi][ri][0] = 0.f; acc[mi][ri][1] = 0.f;
      acc[mi][ri][2] = 0.f; acc[mi][ri][3] = 0.f;
    }

  const bh8* wa = (const bh8*)wl + (size_t)r * 9 * 4 * OM * 64 + lane;

  // 4-deep weight prefetch ring (consume-then-load; validated R3)
  bh8 wqa[4], wqb[4];
  auto wload = [&](int s) {
    int hh = s / 18, tt = s % 18, tp = tt >> 1, kk = tt & 1, ks2 = hh * 2 + kk;
    wqa[s & 3] = wa[(size_t)((tp * 4 + ks2) * OM + 0) * 64];
    if constexpr (OM == 2)
      wqb[s & 3] = wa[(size_t)((tp * 4 + ks2) * OM + 1) * 64];
  };

  // register staging: issue all 6 chunk loads back-to-back (1 latency round-trip)
  bh8 sx[NST];
  auto issue = [&](int half) {
    #pragma unroll
    for (int i = 0; i < NST; ++i) {
      int u = tid + i * 256;
      if (i + 1 < NST || u < NCH) {
        int ch = u & 7; int pix = u >> 3;
        int wr = pix / WC, wc = pix % WC;
        int row = row0 + wr; if (row > H - 1) row = H - 1;
        int col = c0 + wc;  if (col > H - 1) col = H - 1;
        int p = row * H + col;
        sx[i] = *(const bh8*)(xb + (size_t)p * 128 + half * 64 + ch * 8);
      }
    }
  };
  auto wlds = [&](int half) {
    #pragma unroll
    for (int i = 0; i < NST; ++i) {
      int u = tid + i * 256;
      if (i + 1 < NST || u < NCH) {
        int ch = u & 7; int pix = u >> 3;
        float av = att_l[pix];
        bh8 v;
        #pragma unroll
        for (int j2 = 0; j2 < 8; ++j2)
          v[j2] = (short)f2bf(bf2f((unsigned short)sx[i][j2]) * av);
        *(bh8*)&xa[half][pix * CGH + ch * 8] = v;
      }
    }
  };
  auto mfma_half = [&](int half) {
    #pragma unroll
    for (int t = 0; t < 18; ++t) {
      const int s = half * 18 + t;
      // consume ring slot first (locals keep old value live), then prefetch
      bh8 a0 = wqa[s & 3];
      bh8 a1;
      if constexpr (OM == 2) a1 = wqb[s & 3];
      if (s + 4 < 36) wload(s + 4);
      const int tap = t >> 1, kl = t & 1;
      const int ky = tap / 3, kx = tap % 3;
      int pb0 = ((2 * wv + ky) * WC + n + kx) * CGH;
      int pb1 = pb0 + WC * CGH;
      bh8 b0 = *(const bh8*)&xa[half][pb0 + kl * 32 + quad * 8];
      bh8 b1 = *(const bh8*)&xa[half][pb1 + kl * 32 + quad * 8];
      acc[0][0] = __builtin_amdgcn_mfma_f32_16x16x32_bf16(a0, b0, acc[0][0], 0, 0, 0);
      acc[0][1] = __builtin_amdgcn_mfma_f32_16x16x32_bf16(a0, b1, acc[0][1], 0, 0, 0);
      if constexpr (OM == 2) {
        acc[1][0] = __builtin_amdgcn_mfma_f32_16x16x32_bf16(a1, b0, acc[1][0], 0, 0, 0);
        acc[1][1] = __builtin_amdgcn_mfma_f32_16x16x32_bf16(a1, b1, acc[1][1], 0, 0, 0);
      }
    }
  };

  // amap halo staging buffer aliases xa[1] (read before wlds(1) writes it);
  // padded stride RWP: RH*RWP*8 = 3200 ushorts = 6400 B << 24,480 B
  unsigned short* as_l = &xa[1][0];

  // stage this block's rotated attention weights (r fixed)
  for (int i = tid; i < 196; i += 256) {
    int g = i / 49; int t = i % 49;
    int ky = t / 7, kx = t % 7;
    int si, sj; rot_src(r, 7, ky, kx, si, sj);
    int gs = (g - r) & 3;
    wsa_l[g][t] = aw[gs * 49 + si * 7 + sj];
    wsx_l[g][t] = aw[(4 + gs) * 49 + si * 7 + sj];
  }
  // stage amap halo region [row0-3, row0+WR+3) x [c0-3, c0+WC+3), coalesced
  for (int i = tid; i < RH * RW; i += 256) {
    int hr = i / RW, hc = i % RW;
    int gy = row0 - 3 + hr;
    int gx = c0 - 3 + hc;
    bh8 v;
    if ((unsigned)gy < (unsigned)H && (unsigned)gx < (unsigned)H)
      v = *(const bh8*)(ab8 + ((size_t)gy * H + gx) * 8);
    else
      v = (bh8)(short)0;   // never read (tap skip conditions), safe filler
    *(bh8*)&as_l[(hr * RWP + hc) * 8] = v;
  }
  wload(0); wload(1); wload(2); wload(3);
  issue(0);                 // x loads in flight under the att compute
  __syncthreads();          // wsa_l/wsx_l/as_l ready

  // per-tile attention from LDS (tap order verbatim from k_att_gg)
  if (tid < NPIX) {
    int yh = row0 + tid / WC; if (yh > H - 1) yh = H - 1;
    int xw = c0 + tid % WC;   if (xw > H - 1) xw = H - 1;
    float s = 0.f;
    for (int ky = 0; ky < 7; ++ky) {
      int y = yh + ky - 3;
      if ((unsigned)y >= (unsigned)H) continue;
      for (int kx = 0; kx < 7; ++kx) {
        int xx = xw + kx - 3;
        if ((unsigned)xx >= (unsigned)H) continue;
        int tp = ky * 7 + kx;
        bh8 av = *(const bh8*)&as_l[((y - (row0 - 3)) * RWP + (xx - (c0 - 3))) * 8];
        #pragma unroll
        for (int g = 0; g < 4; ++g)
          s += bf2f((unsigned short)av[g]) * wsa_l[g][tp]
             + bf2f((unsigned short)av[4 + g]) * wsx_l[g][tp];
      }
    }
    att_l[tid] = sigmoidf(s);
  }
  __syncthreads();          // att_l ready; as_l readers done

  wlds(0);
  __syncthreads();          // half-0 staged
  issue(1);                 // half-1 loads in flight under half-0 MFMA
  mfma_half(0);
  wlds(1);                  // overwrites xa[1] (= as_l) — readers done above
  __syncthreads();          // half-1 staged
  mfma_half(1);

  // epilogue: C/D col=lane&15 (spatial), row=quad*4+reg (o); c' = r*O + o
  float sv[OM * 4], qv[OM * 4];
  #pragma unroll
  for (int e = 0; e < OM * 4; ++e) { sv[e] = 0.f; qv[e] = 0.f; }
  #pragma unroll
  for (int mi = 0; mi < OM; ++mi)
    #pragma unroll
    for (int ri = 0; ri < 2; ++ri) {
      int prow = row0 + 2 * wv + ri;
      int col = c0 + n;
      if (prow < HO && col < HO) {
        unsigned short* yp = y + ((size_t)b * HO * HO + prow * HO + col) * OSTR;
        int o0 = mi * 16 + quad * 4;
        f4v v = acc[mi][ri];
        if constexpr (O == 32) {
          us4 w4;
          #pragma unroll
          for (int reg = 0; reg < 4; ++reg) {
            float val = v[reg] + bias[o0 + reg];
            w4[reg] = f2bf(val);
            if constexpr (BNS) { sv[mi * 4 + reg] += val; qv[mi * 4 + reg] += val * val; }
          }
          *(us4*)(yp + r * 32 + o0) = w4;
        } else {
          #pragma unroll
          for (int reg = 0; reg < 4; ++reg) {
            int o = o0 + reg;
            if (o < O) yp[r * O + o] = f2bf(v[reg] + bias[o]);
          }
        }
      }
    }

  if constexpr (BNS) {
    #pragma unroll
    for (int e = 0; e < OM * 4; ++e) {
      #pragma unroll
      for (int off = 1; off < 16; off <<= 1) {
        sv[e] += __shfl_xor(sv[e], off);
        qv[e] += __shfl_xor(qv[e], off);
      }
    }
    if (threadIdx.x < 128) bnred[threadIdx.x] = 0.f;
    __syncthreads();
    if (n == 0) {
      #pragma unroll
      for (int e = 0; e < OM * 4; ++e) {
        int o = (e >> 2) * 16 + quad * 4 + (e & 3);
        atomicAdd(&bnred[o], sv[e]);
        atomicAdd(&bnred[64 + o], qv[e]);
      }
    }
    __syncthreads();
    if (threadIdx.x < 128)
      atomicAdd(&partl[(blockIdx.x & 63) * 128 + threadIdx.x], bnred[threadIdx.x]);
  }
}

// ---------------- pixel-parallel post (L1..L6 part A): BN+ReLU(+pool)+amap ----------------
// thread = (output pixel, rotation group g). Same accumulation order as the
// original fused post -> bit-identical. Also serves L1 (HIN=HOUT=46).
template<int HIN, int HOUT, bool POOL>
__global__ void __launch_bounds__(256)
k_postA(const unsigned short* __restrict__ yr, const float* __restrict__ partl,
        const float* __restrict__ gamma, const float* __restrict__ beta,
        unsigned short* __restrict__ xn, unsigned short* __restrict__ amap) {
  __shared__ float st[64];
  __shared__ float l1[256], l2[256];
  bn_finalize_par(partl, gamma, beta, st, l1, l2, 32 * HIN * HIN, threadIdx.x);
  int idx = blockIdx.x * 256 + threadIdx.x;
  if (idx >= 32 * HOUT * HOUT * 4) return;
  int g = idx & 3; int p = idx >> 2;
  int col = p % HOUT; int t = p / HOUT;
  int row = t % HOUT; int b = t / HOUT;
  float sm = 0.f, mx = -1e30f;
  unsigned short* xp = xn + (size_t)p * 128 + g * 32;
  if constexpr (POOL) {
    const unsigned short* p00 =
        yr + ((size_t)b * HIN * HIN + (row * 2) * HIN + col * 2) * 128 + g * 32;
    #pragma unroll
    for (int k = 0; k < 4; ++k) {
      bh8 r0 = *(const bh8*)(p00 + k * 8);
      bh8 r1 = *(const bh8*)(p00 + 128 + k * 8);
      bh8 r2 = *(const bh8*)(p00 + (size_t)HIN * 128 + k * 8);
      bh8 r3 = *(const bh8*)(p00 + (size_t)(HIN + 1) * 128 + k * 8);
      bh8 w;
      #pragma unroll
      for (int e = 0; e < 8; ++e) {
        float sc = st[k * 8 + e], sh = st[32 + k * 8 + e];
        float a0 = fmaxf(fmaf(bf2f((unsigned short)r0[e]), sc, sh), 0.f);
        float a1 = fmaxf(fmaf(bf2f((unsigned short)r1[e]), sc, sh), 0.f);
        float a2 = fmaxf(fmaf(bf2f((unsigned short)r2[e]), sc, sh), 0.f);
        float a3 = fmaxf(fmaf(bf2f((unsigned short)r3[e]), sc, sh), 0.f);
        float val = fmaxf(fmaxf(a0, a1), fmaxf(a2, a3));
        w[e] = (short)f2bf(val);
        sm += val; mx = fmaxf(mx, val);
      }
      *(bh8*)(xp + k * 8) = w;
    }
  } else {
    const unsigned short* yp = yr + (size_t)p * 128 + g * 32;
    #pragma unroll
    for (int k = 0; k < 4; ++k) {
      bh8 raw = *(const bh8*)(yp + k * 8);
      bh8 w;
      #pragma unroll
      for (int e = 0; e < 8; ++e) {
        float v = fmaxf(fmaf(bf2f((unsigned short)raw[e]), st[k * 8 + e], st[32 + k * 8 + e]), 0.f);
        w[e] = (short)f2bf(v);
        sm += v;
        mx = fmaxf(mx, v);
      }
      *(bh8*)(xp + k * 8) = w;
    }
  }
  amap[(size_t)p * 8 + g] = f2bf(sm * (1.f / 32.f));
  amap[(size_t)p * 8 + 4 + g] = f2bf(mx);
}

// ---------------- final: rotation max + spatial mean ----------------
__global__ void k_final(const unsigned short* __restrict__ y7, float* __restrict__ out) {
  int idx = blockIdx.x * blockDim.x + threadIdx.x;
  if (idx >= 320) return;
  int o = idx % 10; int b = idx / 10;
  const unsigned short* p = y7 + (size_t)b * 144 * 40;
  float s = 0.f;
  for (int sp = 0; sp < 144; ++sp) {
    const unsigned short* q = p + sp * 40 + o;
    float m = fmaxf(fmaxf(bf2f(q[0]), bf2f(q[10])), fmaxf(bf2f(q[20]), bf2f(q[30])));
    s += m;
  }
  out[idx] = s * (1.f / 144.f);
}

// ---------------- host ----------------

extern "C" void kernel_launch(void* const* d_in, const int* in_sizes, int n_in,
                              void* d_out, int out_size, void* d_ws, size_t ws_size,
                              hipStream_t stream) {
  (void)in_sizes; (void)n_in; (void)out_size; (void)ws_size;
  const float* x   = (const float*)d_in[0];
  const float* w1  = (const float*)d_in[1];
  const float* b1  = (const float*)d_in[2];
  const float* aw1 = (const float*)d_in[3];
  const float* W[6];  const float* BI[6]; const float* AW[6];
  for (int i = 0; i < 6; ++i) {
    W[i]  = (const float*)d_in[4 + 3 * i];
    BI[i] = (const float*)d_in[5 + 3 * i];
    AW[i] = (const float*)d_in[6 + 3 * i];
  }
  const float* G[6]; const float* BE[6];
  for (int i = 0; i < 6; ++i) {
    G[i]  = (const float*)d_in[22 + 2 * i];
    BE[i] = (const float*)d_in[23 + 2 * i];
  }
  float* out = (float*)d_out;

  // workspace (floats): ~38.8 MB
  float* ws = (float*)d_ws;
  unsigned short* YR = (unsigned short*)ws;                  // raw conv out bf16
  unsigned short* XN = (unsigned short*)(ws + 4333568);      // normalized xn bf16
  unsigned short* AMAP = (unsigned short*)(ws + 8667136);    // amap, 541,696 ush
  float* ATT = ws + 8937984;                                 // 294,912 (L1 lift only)
  unsigned short* WROT = (unsigned short*)(ws + 9232896);    // 811,008 ush
  float* PART  = ws + 9638400;                               // 6 layers x 8192

  auto cdiv = [](int a, int b) { return (a + b - 1) / b; };
  float* PL[6];
  for (int i = 0; i < 6; ++i) PL[i] = PART + i * 8192;

  // packed: weight prep (3168) + L1 attention (1024) + PART zero (24)
  k_prep_att<<<dim3(4216), dim3(256), 0, stream>>>(
      W[0], W[1], W[2], W[3], W[4], W[5], WROT, x, aw1, ATT, PART);
  const unsigned short* WL[6];
  for (int i = 0; i < 5; ++i) WL[i] = WROT + i * 147456;
  WL[5] = WROT + 737280;

  // ---- layer 1: lifting conv (stats fused) + pixel-parallel post ----
  k_conv_lift<<<dim3(32 * 46), dim3(256), 0, stream>>>(x, ATT, w1, b1, YR, PL[0]);
  k_postA<46, 46, false><<<dim3(cdiv(32 * 46 * 46 * 4, 256)), dim3(256), 0, stream>>>(YR, PL[0], G[0], BE[0], XN, AMAP);
  // ---- layer 2 (H=46 -> 44, att fused from AMAP+AW[0]) + post (pool) ----
  k_conv_mfma<46, 2, 32, 128, true><<<dim3(128 * 6 * 3), dim3(256), 0, stream>>>(XN, AMAP, AW[0], WL[0], BI[0], YR, PL[1]);
  k_postA<44, 22, true><<<dim3(cdiv(32 * 22 * 22 * 4, 256)), dim3(256), 0, stream>>>(YR, PL[1], G[1], BE[1], XN, AMAP);
  // ---- layer 3 (22 -> 20) ----
  k_conv_mfma<22, 2, 32, 128, true><<<dim3(128 * 3 * 2), dim3(256), 0, stream>>>(XN, AMAP, AW[1], WL[1], BI[1], YR, PL[2]);
  k_postA<20, 20, false><<<dim3(cdiv(32 * 20 * 20 * 4, 256)), dim3(256), 0, stream>>>(YR, PL[2], G[2], BE[2], XN, AMAP);
  // ---- layer 4 (20 -> 18) ----
  k_conv_mfma<20, 2, 32, 128, true><<<dim3(128 * 3 * 2), dim3(256), 0, stream>>>(XN, AMAP, AW[2], WL[2], BI[2], YR, PL[3]);
  k_postA<18, 18, false><<<dim3(cdiv(32 * 18 * 18 * 4, 256)), dim3(256), 0, stream>>>(YR, PL[3], G[3], BE[3], XN, AMAP);
  // ---- layer 5 (18 -> 16) ----
  k_conv_mfma<18, 2, 32, 128, true><<<dim3(128 * 2 * 1), dim3(256), 0, stream>>>(XN, AMAP, AW[3], WL[3], BI[3], YR, PL[4]);
  k_postA<16, 16, false><<<dim3(cdiv(32 * 16 * 16 * 4, 256)), dim3(256), 0, stream>>>(YR, PL[4], G[4], BE[4], XN, AMAP);
  // ---- layer 6 (16 -> 14) ----
  k_conv_mfma<16, 2, 32, 128, true><<<dim3(128 * 2 * 1), dim3(256), 0, stream>>>(XN, AMAP, AW[4], WL[4], BI[4], YR, PL[5]);
  k_postA<14, 14, false><<<dim3(cdiv(32 * 14 * 14 * 4, 256)), dim3(256), 0, stream>>>(YR, PL[5], G[5], BE[5], XN, AMAP);
  // ---- layer 7 (14 -> 12, O=10, no BN) ----
  k_conv_mfma<14, 1, 10, 40, false><<<dim3(128 * 2 * 1), dim3(256), 0, stream>>>(XN, AMAP, AW[5], WL[5], BI[5], YR, nullptr);
  // ---- rotation max + spatial mean ----
  k_final<<<dim3(5), dim3(64), 0, stream>>>(YR, out);
}